// Round 1
// baseline (1039.956 us; speedup 1.0000x reference)
//
#include <hip/hip_runtime.h>
#include <cstdint>

#define N_NODES 100000
#define N_EDGES 1600000
#define HID 128
#define NT 32

// ---------------- CSR build ----------------
__global__ void k_hist(const int* __restrict__ dst, int* __restrict__ counts, int n) {
    int e = blockIdx.x * blockDim.x + threadIdx.x;
    if (e < n) atomicAdd(&counts[dst[e]], 1);
}

__global__ void k_scan1(const int* __restrict__ in, int* __restrict__ excl,
                        int* __restrict__ blksum, int n) {
    __shared__ int s[1024];
    int tid = threadIdx.x;
    int gid = blockIdx.x * 1024 + tid;
    int v = (gid < n) ? in[gid] : 0;
    s[tid] = v;
    __syncthreads();
    #pragma unroll 1
    for (int d = 1; d < 1024; d <<= 1) {
        int t = (tid >= d) ? s[tid - d] : 0;
        __syncthreads();
        s[tid] += t;
        __syncthreads();
    }
    if (gid < n) excl[gid] = s[tid] - v;
    if (tid == 1023) blksum[blockIdx.x] = s[1023];
}

__global__ void k_scan2(int* __restrict__ blksum, int nb) {
    __shared__ int s[1024];
    int tid = threadIdx.x;
    int v = (tid < nb) ? blksum[tid] : 0;
    s[tid] = v;
    __syncthreads();
    #pragma unroll 1
    for (int d = 1; d < 1024; d <<= 1) {
        int t = (tid >= d) ? s[tid - d] : 0;
        __syncthreads();
        s[tid] += t;
        __syncthreads();
    }
    if (tid < nb) blksum[tid] = s[tid] - v;
}

__global__ void k_scan3(int* __restrict__ offsets, const int* __restrict__ blksum,
                        int* __restrict__ cursor, int n, int total) {
    int gid = blockIdx.x * 1024 + threadIdx.x;
    if (gid < n) {
        int o = offsets[gid] + blksum[blockIdx.x];
        offsets[gid] = o;
        cursor[gid] = o;
    }
    if (gid == 0) offsets[n] = total;
}

__global__ void k_fill(const int* __restrict__ src, const int* __restrict__ dst,
                       int* __restrict__ cursor, int* __restrict__ csr, int n) {
    int e = blockIdx.x * blockDim.x + threadIdx.x;
    if (e < n) {
        int p = atomicAdd(&cursor[dst[e]], 1);
        csr[p] = src[e];
    }
}

// ---------------- aggregation (pull over CSR) ----------------
// one wave per node; lane handles 2 channels (128 ch / 64 lanes)
__global__ void k_agg(const float* __restrict__ X, const int* __restrict__ offsets,
                      const int* __restrict__ csr, float* __restrict__ agg, int n) {
    int node = blockIdx.x * 4 + (threadIdx.x >> 6);
    if (node >= n) return;
    int lane = threadIdx.x & 63;
    int e0 = offsets[node], e1 = offsets[node + 1];
    float ax = 0.f, ay = 0.f;
    for (int e = e0; e < e1; ++e) {
        int s = csr[e];
        const float2 v = *reinterpret_cast<const float2*>(X + (size_t)s * HID + (size_t)lane * 2);
        ax += v.x;
        ay += v.y;
    }
    float2 o;
    o.x = ax; o.y = ay;
    *reinterpret_cast<float2*>(agg + (size_t)node * HID + (size_t)lane * 2) = o;
}

// ---------------- fused dual-source GEMM: Out = relu?(Xa@Wa + Xb@Wb + bias) ----------------
// M x 128 output, K = 128 per source, all row-major f32.
// 256 threads, 64-row tile. thread: cols tx*4..+3 (tx=t&31), rows ty*8..+7 (ty=t>>5).
__global__ __launch_bounds__(256) void k_gemm128(
    const float* __restrict__ Xa, const float* __restrict__ Wa,
    const float* __restrict__ Xb, const float* __restrict__ Wb,
    const float* __restrict__ bias, float* __restrict__ Out,
    int M, int doRelu)
{
    __shared__ float  Ast[32 * 72];   // A chunk transposed: [k][row], pad 72
    __shared__ float4 Ws4[32 * 33];   // W chunk: [k][col4], 32 f4 + 1 pad

    const int t = threadIdx.x;
    const int tx = t & 31;
    const int ty = t >> 5;
    const int r0 = blockIdx.x * 64;
    const int srow = t >> 2;          // staging row 0..63
    const int scg  = t & 3;           // staging k-octet 0..3

    float acc[8][4];
    #pragma unroll
    for (int i = 0; i < 8; ++i)
        #pragma unroll
        for (int j = 0; j < 4; ++j) acc[i][j] = 0.f;

    #pragma unroll 1
    for (int sidx = 0; sidx < 2; ++sidx) {
        const float* __restrict__ X = sidx ? Xb : Xa;
        const float* __restrict__ W = sidx ? Wb : Wa;
        if (X == nullptr) break;
        #pragma unroll 1
        for (int kc = 0; kc < 4; ++kc) {
            __syncthreads();
            // stage A chunk (transposed into LDS)
            {
                float4 v0 = {0.f, 0.f, 0.f, 0.f}, v1 = {0.f, 0.f, 0.f, 0.f};
                if (r0 + srow < M) {
                    const float* p = X + (size_t)(r0 + srow) * 128 + kc * 32 + scg * 8;
                    v0 = *reinterpret_cast<const float4*>(p);
                    v1 = *reinterpret_cast<const float4*>(p + 4);
                }
                const int kb = scg * 8;
                Ast[(kb + 0) * 72 + srow] = v0.x;
                Ast[(kb + 1) * 72 + srow] = v0.y;
                Ast[(kb + 2) * 72 + srow] = v0.z;
                Ast[(kb + 3) * 72 + srow] = v0.w;
                Ast[(kb + 4) * 72 + srow] = v1.x;
                Ast[(kb + 5) * 72 + srow] = v1.y;
                Ast[(kb + 6) * 72 + srow] = v1.z;
                Ast[(kb + 7) * 72 + srow] = v1.w;
            }
            // stage W chunk
            {
                const int kk = t >> 3;            // 0..31
                const int cc = (t & 7) * 16;      // 0..112 step 16
                const float* wp = W + (size_t)(kc * 32 + kk) * 128 + cc;
                #pragma unroll
                for (int j = 0; j < 4; ++j)
                    Ws4[kk * 33 + (cc >> 2) + j] = *reinterpret_cast<const float4*>(wp + 4 * j);
            }
            __syncthreads();
            #pragma unroll 8
            for (int k = 0; k < 32; ++k) {
                float4 a0 = *reinterpret_cast<const float4*>(&Ast[k * 72 + ty * 8]);
                float4 a1 = *reinterpret_cast<const float4*>(&Ast[k * 72 + ty * 8 + 4]);
                float4 w  = Ws4[k * 33 + tx];
                const float av[8] = {a0.x, a0.y, a0.z, a0.w, a1.x, a1.y, a1.z, a1.w};
                #pragma unroll
                for (int i = 0; i < 8; ++i) {
                    acc[i][0] += av[i] * w.x;
                    acc[i][1] += av[i] * w.y;
                    acc[i][2] += av[i] * w.z;
                    acc[i][3] += av[i] * w.w;
                }
            }
        }
    }
    // epilogue: bias + optional relu + store
    float4 b4 = *reinterpret_cast<const float4*>(&bias[tx * 4]);
    #pragma unroll
    for (int i = 0; i < 8; ++i) {
        int r = r0 + ty * 8 + i;
        if (r < M) {
            float4 o;
            o.x = acc[i][0] + b4.x;
            o.y = acc[i][1] + b4.y;
            o.z = acc[i][2] + b4.z;
            o.w = acc[i][3] + b4.w;
            if (doRelu) {
                o.x = fmaxf(o.x, 0.f); o.y = fmaxf(o.y, 0.f);
                o.z = fmaxf(o.z, 0.f); o.w = fmaxf(o.w, 0.f);
            }
            *reinterpret_cast<float4*>(&Out[(size_t)r * 128 + tx * 4]) = o;
        }
    }
}

// ---------------- classifier head: Out[M x 32] = X@W + bias ----------------
__global__ __launch_bounds__(256) void k_gemm32(
    const float* __restrict__ X, const float* __restrict__ W,
    const float* __restrict__ bias, float* __restrict__ Out, int M)
{
    __shared__ float  Xst[32 * 72];
    __shared__ float4 Ws4[128 * 9];   // whole W: [k][col4], 8 f4 + 1 pad

    const int t = threadIdx.x;
    const int tx = t & 7;             // cols tx*4..+3
    const int ty = t >> 3;            // rows ty*2..+1
    const int r0 = blockIdx.x * 64;
    const int srow = t >> 2, scg = t & 3;

    // stage whole W (128 x 32) once
    {
        const int kk = t >> 1;            // 0..127
        const int cc = (t & 1) * 16;      // 0 or 16
        const float* wp = W + (size_t)kk * 32 + cc;
        #pragma unroll
        for (int j = 0; j < 4; ++j)
            Ws4[kk * 9 + (cc >> 2) + j] = *reinterpret_cast<const float4*>(wp + 4 * j);
    }

    float acc[2][4];
    #pragma unroll
    for (int i = 0; i < 2; ++i)
        #pragma unroll
        for (int j = 0; j < 4; ++j) acc[i][j] = 0.f;

    #pragma unroll 1
    for (int kc = 0; kc < 4; ++kc) {
        __syncthreads();
        {
            float4 v0 = {0.f, 0.f, 0.f, 0.f}, v1 = {0.f, 0.f, 0.f, 0.f};
            if (r0 + srow < M) {
                const float* p = X + (size_t)(r0 + srow) * 128 + kc * 32 + scg * 8;
                v0 = *reinterpret_cast<const float4*>(p);
                v1 = *reinterpret_cast<const float4*>(p + 4);
            }
            const int kb = scg * 8;
            Xst[(kb + 0) * 72 + srow] = v0.x;
            Xst[(kb + 1) * 72 + srow] = v0.y;
            Xst[(kb + 2) * 72 + srow] = v0.z;
            Xst[(kb + 3) * 72 + srow] = v0.w;
            Xst[(kb + 4) * 72 + srow] = v1.x;
            Xst[(kb + 5) * 72 + srow] = v1.y;
            Xst[(kb + 6) * 72 + srow] = v1.z;
            Xst[(kb + 7) * 72 + srow] = v1.w;
        }
        __syncthreads();
        #pragma unroll 8
        for (int k = 0; k < 32; ++k) {
            float2 a = *reinterpret_cast<const float2*>(&Xst[k * 72 + ty * 2]);
            float4 w = Ws4[(kc * 32 + k) * 9 + tx];
            acc[0][0] += a.x * w.x; acc[0][1] += a.x * w.y;
            acc[0][2] += a.x * w.z; acc[0][3] += a.x * w.w;
            acc[1][0] += a.y * w.x; acc[1][1] += a.y * w.y;
            acc[1][2] += a.y * w.z; acc[1][3] += a.y * w.w;
        }
    }
    float4 b4 = *reinterpret_cast<const float4*>(&bias[tx * 4]);
    #pragma unroll
    for (int i = 0; i < 2; ++i) {
        int r = r0 + ty * 2 + i;
        if (r < M) {
            float4 o;
            o.x = acc[i][0] + b4.x;
            o.y = acc[i][1] + b4.y;
            o.z = acc[i][2] + b4.z;
            o.w = acc[i][3] + b4.w;
            *reinterpret_cast<float4*>(&Out[(size_t)r * 32 + tx * 4]) = o;
        }
    }
}

extern "C" void kernel_launch(void* const* d_in, const int* in_sizes, int n_in,
                              void* d_out, int out_size, void* d_ws, size_t ws_size,
                              hipStream_t stream) {
    (void)in_sizes; (void)n_in; (void)out_size; (void)ws_size;

    const float* x      = (const float*)d_in[0];
    const int*   ei     = (const int*)d_in[1];
    const float* Wrel0  = (const float*)d_in[2];
    const float* brel0  = (const float*)d_in[3];
    const float* Wroot0 = (const float*)d_in[4];
    const float* Wrel1  = (const float*)d_in[5];
    const float* brel1  = (const float*)d_in[6];
    const float* Wroot1 = (const float*)d_in[7];
    const float* Wrel2  = (const float*)d_in[8];
    const float* brel2  = (const float*)d_in[9];
    const float* Wroot2 = (const float*)d_in[10];
    const float* Wc0    = (const float*)d_in[11];
    const float* bc0    = (const float*)d_in[12];
    const float* Wc1    = (const float*)d_in[13];
    const float* bc1    = (const float*)d_in[14];

    const int* src = ei;
    const int* dst = ei + N_EDGES;

    char* w = (char*)d_ws;
    auto alloc = [&](size_t bytes) {
        char* p = w;
        w += (bytes + 255) & ~(size_t)255;
        return (void*)p;
    };
    int*   cursor  = (int*)alloc((size_t)N_NODES * 4);          // counts, then fill cursor
    int*   offsets = (int*)alloc(((size_t)N_NODES + 1) * 4);
    int*   blksum  = (int*)alloc(1024 * 4);
    int*   csr     = (int*)alloc((size_t)N_EDGES * 4);
    float* agg     = (float*)alloc((size_t)N_NODES * HID * 4);
    float* hA      = (float*)alloc((size_t)N_NODES * HID * 4);
    float* hB      = (float*)alloc((size_t)N_NODES * HID * 4);

    hipMemsetAsync(cursor, 0, (size_t)N_NODES * 4, stream);
    const int eb = (N_EDGES + 255) / 256;
    const int sb = (N_NODES + 1023) / 1024;
    k_hist<<<eb, 256, 0, stream>>>(dst, cursor, N_EDGES);
    k_scan1<<<sb, 1024, 0, stream>>>(cursor, offsets, blksum, N_NODES);
    k_scan2<<<1, 1024, 0, stream>>>(blksum, sb);
    k_scan3<<<sb, 1024, 0, stream>>>(offsets, blksum, cursor, N_NODES, N_EDGES);
    k_fill<<<eb, 256, 0, stream>>>(src, dst, cursor, csr, N_EDGES);

    const int ab = (N_NODES + 3) / 4;
    const int gb = (N_NODES + 63) / 64;

    // layer 0: h = relu(agg(x)@Wrel0 + b + x@Wroot0)
    k_agg<<<ab, 256, 0, stream>>>(x, offsets, csr, agg, N_NODES);
    k_gemm128<<<gb, 256, 0, stream>>>(agg, Wrel0, x, Wroot0, brel0, hA, N_NODES, 1);
    // layer 1
    k_agg<<<ab, 256, 0, stream>>>(hA, offsets, csr, agg, N_NODES);
    k_gemm128<<<gb, 256, 0, stream>>>(agg, Wrel1, hA, Wroot1, brel1, hB, N_NODES, 1);
    // layer 2
    k_agg<<<ab, 256, 0, stream>>>(hB, offsets, csr, agg, N_NODES);
    k_gemm128<<<gb, 256, 0, stream>>>(agg, Wrel2, hB, Wroot2, brel2, hA, N_NODES, 1);
    // classifier hidden: hc = relu(h@Wc0 + bc0)  (reuse hB)
    k_gemm128<<<gb, 256, 0, stream>>>(hA, Wc0, nullptr, nullptr, bc0, hB, N_NODES, 1);
    // classifier out: logits = hc@Wc1 + bc1
    k_gemm32<<<gb, 256, 0, stream>>>(hB, Wc1, bc1, (float*)d_out, N_NODES);
}

// Round 3
// 566.059 us; speedup vs baseline: 1.8372x; 1.8372x over previous
//
#include <hip/hip_runtime.h>
#include <cstdint>

#define N_NODES 100000
#define N_EDGES 1600000
#define HID 128
#define NT 32

typedef __attribute__((ext_vector_type(8))) short short8v;
typedef __attribute__((ext_vector_type(4))) float f32x4;

__device__ inline unsigned short f2bf(float f) {
    union { float f; unsigned u; } v; v.f = f;
    unsigned r = v.u + 0x7FFF + ((v.u >> 16) & 1);
    return (unsigned short)(r >> 16);
}
__device__ inline float bf2f(unsigned short u) {
    union { unsigned u; float f; } v; v.u = ((unsigned)u) << 16; return v.f;
}

// ---------------- CSR build ----------------
__global__ void k_hist(const int* __restrict__ dst, int* __restrict__ counts, int n) {
    int e = blockIdx.x * blockDim.x + threadIdx.x;
    if (e < n) atomicAdd(&counts[dst[e]], 1);
}

__global__ void k_scan1(const int* __restrict__ in, int* __restrict__ excl,
                        int* __restrict__ blksum, int n) {
    __shared__ int s[1024];
    int tid = threadIdx.x;
    int gid = blockIdx.x * 1024 + tid;
    int v = (gid < n) ? in[gid] : 0;
    s[tid] = v;
    __syncthreads();
    #pragma unroll 1
    for (int d = 1; d < 1024; d <<= 1) {
        int t = (tid >= d) ? s[tid - d] : 0;
        __syncthreads();
        s[tid] += t;
        __syncthreads();
    }
    if (gid < n) excl[gid] = s[tid] - v;
    if (tid == 1023) blksum[blockIdx.x] = s[1023];
}

__global__ void k_scan2(int* __restrict__ blksum, int nb) {
    __shared__ int s[1024];
    int tid = threadIdx.x;
    int v = (tid < nb) ? blksum[tid] : 0;
    s[tid] = v;
    __syncthreads();
    #pragma unroll 1
    for (int d = 1; d < 1024; d <<= 1) {
        int t = (tid >= d) ? s[tid - d] : 0;
        __syncthreads();
        s[tid] += t;
        __syncthreads();
    }
    if (tid < nb) blksum[tid] = s[tid] - v;
}

__global__ void k_scan3(int* __restrict__ offsets, const int* __restrict__ blksum,
                        int* __restrict__ cursor, int n, int total) {
    int gid = blockIdx.x * 1024 + threadIdx.x;
    if (gid < n) {
        int o = offsets[gid] + blksum[blockIdx.x];
        offsets[gid] = o;
        cursor[gid] = o;
    }
    if (gid == 0) offsets[n] = total;
}

__global__ void k_fill(const int* __restrict__ src, const int* __restrict__ dst,
                       int* __restrict__ cursor, int* __restrict__ csr, int n) {
    int e = blockIdx.x * blockDim.x + threadIdx.x;
    if (e < n) {
        int p = atomicAdd(&cursor[dst[e]], 1);
        csr[p] = src[e];
    }
}

// ---------------- cast x -> bf16 ----------------
__global__ void k_cast(const float* __restrict__ in, unsigned short* __restrict__ out, int n8) {
    int i = blockIdx.x * 256 + threadIdx.x;
    if (i >= n8) return;
    const float4* p = reinterpret_cast<const float4*>(in + (size_t)i * 8);
    float4 a = p[0], b = p[1];
    union { unsigned short u[8]; uint4 v; } o;
    o.u[0] = f2bf(a.x); o.u[1] = f2bf(a.y); o.u[2] = f2bf(a.z); o.u[3] = f2bf(a.w);
    o.u[4] = f2bf(b.x); o.u[5] = f2bf(b.y); o.u[6] = f2bf(b.z); o.u[7] = f2bf(b.w);
    *reinterpret_cast<uint4*>(out + (size_t)i * 8) = o.v;
}

// ---------------- weight prep: Wt[n][k] = bf16(W[k][n]), K=128 ----------------
struct WPrepArgs {
    const float* src[7];
    unsigned short* dst[7];
    int Ndim[7];
};

__global__ void k_prep_w(WPrepArgs a) {
    int m = blockIdx.x;
    const float* s = a.src[m];
    unsigned short* d = a.dst[m];
    int N = a.Ndim[m];
    int total = 128 * N;
    for (int idx = threadIdx.x; idx < total; idx += 256) {
        int n = idx >> 7;       // 0..N-1
        int k = idx & 127;      // 0..127
        d[n * 128 + k] = f2bf(s[(size_t)k * N + n]);
    }
}

// ---------------- aggregation (pull over CSR, bf16) ----------------
// one wave per node; lane handles 2 channels (uint = 2 bf16)
__global__ void k_agg_bf(const unsigned short* __restrict__ X, const int* __restrict__ offsets,
                         const int* __restrict__ csr, unsigned short* __restrict__ agg, int n) {
    int node = blockIdx.x * 4 + (threadIdx.x >> 6);
    if (node >= n) return;
    int lane = threadIdx.x & 63;
    int e0 = offsets[node], e1 = offsets[node + 1];
    float ax = 0.f, ay = 0.f;
    int e = e0;
    for (; e + 4 <= e1; e += 4) {
        int s0 = csr[e], s1 = csr[e + 1], s2 = csr[e + 2], s3 = csr[e + 3];
        unsigned v0 = *reinterpret_cast<const unsigned*>(X + (size_t)s0 * HID + lane * 2);
        unsigned v1 = *reinterpret_cast<const unsigned*>(X + (size_t)s1 * HID + lane * 2);
        unsigned v2 = *reinterpret_cast<const unsigned*>(X + (size_t)s2 * HID + lane * 2);
        unsigned v3 = *reinterpret_cast<const unsigned*>(X + (size_t)s3 * HID + lane * 2);
        ax += bf2f((unsigned short)(v0 & 0xFFFF)) + bf2f((unsigned short)(v1 & 0xFFFF))
            + bf2f((unsigned short)(v2 & 0xFFFF)) + bf2f((unsigned short)(v3 & 0xFFFF));
        ay += bf2f((unsigned short)(v0 >> 16)) + bf2f((unsigned short)(v1 >> 16))
            + bf2f((unsigned short)(v2 >> 16)) + bf2f((unsigned short)(v3 >> 16));
    }
    for (; e < e1; ++e) {
        int s = csr[e];
        unsigned v = *reinterpret_cast<const unsigned*>(X + (size_t)s * HID + lane * 2);
        ax += bf2f((unsigned short)(v & 0xFFFF));
        ay += bf2f((unsigned short)(v >> 16));
    }
    unsigned pack = ((unsigned)f2bf(ay) << 16) | (unsigned)f2bf(ax);
    *reinterpret_cast<unsigned*>(agg + (size_t)node * HID + lane * 2) = pack;
}

// ---------------- MFMA dual-source GEMM: Out = relu?(Xa@Wa + Xb@Wb + bias) ----------------
// BM=128 (4 waves x 32 rows), N=128, K=128 per source. Wt is [n][k] bf16.
__global__ __launch_bounds__(256) void k_mfma128(
    const unsigned short* __restrict__ Xa, const unsigned short* __restrict__ WtA,
    const unsigned short* __restrict__ Xb, const unsigned short* __restrict__ WtB,
    const float* __restrict__ bias, unsigned short* __restrict__ Out,
    int M, int doRelu)
{
    __shared__ unsigned short wlds[128 * 136];

    const int t = threadIdx.x;
    const int lane = t & 63;
    const int w = t >> 6;
    const int r0 = blockIdx.x * 128;
    const int lrow = lane & 15;
    const int kg = lane >> 4;      // 0..3

    f32x4 acc[2][8];
    #pragma unroll
    for (int i = 0; i < 2; ++i)
        #pragma unroll
        for (int f = 0; f < 8; ++f) acc[i][f] = (f32x4){0.f, 0.f, 0.f, 0.f};

    #pragma unroll 1
    for (int sidx = 0; sidx < 2; ++sidx) {
        const unsigned short* X  = sidx ? Xb : Xa;
        const unsigned short* Wt = sidx ? WtB : WtA;
        if (!X) break;
        __syncthreads();
        // stage Wt [128][128] -> wlds [128][136]; each thread copies 64 shorts
        // via 8 x uint4 (8-short) stores. NOTE: stride is 8 shorts (16 B).
        {
            int n = t >> 1;
            int half = (t & 1) * 64;
            const unsigned short* srcp = Wt + (size_t)n * 128 + half;
            unsigned short* dstp = &wlds[n * 136 + half];
            #pragma unroll
            for (int j = 0; j < 8; ++j)
                *reinterpret_cast<uint4*>(dstp + j * 8) =
                    *reinterpret_cast<const uint4*>(srcp + j * 8);
        }
        __syncthreads();
        #pragma unroll 1
        for (int kc = 0; kc < 4; ++kc) {
            const int kb = kc * 32 + kg * 8;
            short8v a0 = {0,0,0,0,0,0,0,0}, a1 = {0,0,0,0,0,0,0,0};
            int row0 = r0 + w * 32 + lrow;
            int row1 = row0 + 16;
            if (row0 < M) a0 = *reinterpret_cast<const short8v*>(X + (size_t)row0 * 128 + kb);
            if (row1 < M) a1 = *reinterpret_cast<const short8v*>(X + (size_t)row1 * 128 + kb);
            #pragma unroll
            for (int f = 0; f < 8; ++f) {
                short8v b = *reinterpret_cast<const short8v*>(&wlds[(f * 16 + lrow) * 136 + kb]);
                acc[0][f] = __builtin_amdgcn_mfma_f32_16x16x32_bf16(a0, b, acc[0][f], 0, 0, 0);
                acc[1][f] = __builtin_amdgcn_mfma_f32_16x16x32_bf16(a1, b, acc[1][f], 0, 0, 0);
            }
        }
    }
    // epilogue: bias + relu + bf16 store. D: row=kg*4+reg, col=f*16+lrow
    #pragma unroll
    for (int rr = 0; rr < 2; ++rr) {
        #pragma unroll
        for (int f = 0; f < 8; ++f) {
            int col = f * 16 + lrow;
            float bv = bias[col];
            #pragma unroll
            for (int reg = 0; reg < 4; ++reg) {
                int row = r0 + w * 32 + rr * 16 + kg * 4 + reg;
                if (row < M) {
                    float v = acc[rr][f][reg] + bv;
                    if (doRelu) v = fmaxf(v, 0.f);
                    Out[(size_t)row * 128 + col] = f2bf(v);
                }
            }
        }
    }
}

// ---------------- MFMA head: Out[M x 32] f32 = X@Wc1 + bc1 ----------------
__global__ __launch_bounds__(256) void k_mfma32(
    const unsigned short* __restrict__ X, const unsigned short* __restrict__ Wt,
    const float* __restrict__ bias, float* __restrict__ Out, int M)
{
    __shared__ unsigned short wlds[32 * 136];

    const int t = threadIdx.x;
    const int lane = t & 63;
    const int w = t >> 6;
    const int r0 = blockIdx.x * 128;
    const int lrow = lane & 15;
    const int kg = lane >> 4;

    // stage Wt [32][128]
    {
        int n = t >> 3;               // 0..31
        int seg = (t & 7) * 16;       // 0..112 step 16
        *reinterpret_cast<uint4*>(&wlds[n * 136 + seg]) =
            *reinterpret_cast<const uint4*>(Wt + (size_t)n * 128 + seg);
        *reinterpret_cast<uint4*>(&wlds[n * 136 + seg + 8]) =
            *reinterpret_cast<const uint4*>(Wt + (size_t)n * 128 + seg + 8);
    }
    __syncthreads();

    f32x4 acc[2][2];
    #pragma unroll
    for (int i = 0; i < 2; ++i)
        #pragma unroll
        for (int f = 0; f < 2; ++f) acc[i][f] = (f32x4){0.f, 0.f, 0.f, 0.f};

    #pragma unroll 1
    for (int kc = 0; kc < 4; ++kc) {
        const int kb = kc * 32 + kg * 8;
        short8v a0 = {0,0,0,0,0,0,0,0}, a1 = {0,0,0,0,0,0,0,0};
        int row0 = r0 + w * 32 + lrow;
        int row1 = row0 + 16;
        if (row0 < M) a0 = *reinterpret_cast<const short8v*>(X + (size_t)row0 * 128 + kb);
        if (row1 < M) a1 = *reinterpret_cast<const short8v*>(X + (size_t)row1 * 128 + kb);
        #pragma unroll
        for (int f = 0; f < 2; ++f) {
            short8v b = *reinterpret_cast<const short8v*>(&wlds[(f * 16 + lrow) * 136 + kb]);
            acc[0][f] = __builtin_amdgcn_mfma_f32_16x16x32_bf16(a0, b, acc[0][f], 0, 0, 0);
            acc[1][f] = __builtin_amdgcn_mfma_f32_16x16x32_bf16(a1, b, acc[1][f], 0, 0, 0);
        }
    }
    #pragma unroll
    for (int rr = 0; rr < 2; ++rr) {
        #pragma unroll
        for (int f = 0; f < 2; ++f) {
            int col = f * 16 + lrow;
            float bv = bias[col];
            #pragma unroll
            for (int reg = 0; reg < 4; ++reg) {
                int row = r0 + w * 32 + rr * 16 + kg * 4 + reg;
                if (row < M) Out[(size_t)row * 32 + col] = acc[rr][f][reg] + bv;
            }
        }
    }
}

extern "C" void kernel_launch(void* const* d_in, const int* in_sizes, int n_in,
                              void* d_out, int out_size, void* d_ws, size_t ws_size,
                              hipStream_t stream) {
    (void)in_sizes; (void)n_in; (void)out_size; (void)ws_size;

    const float* x      = (const float*)d_in[0];
    const int*   ei     = (const int*)d_in[1];
    const float* Wrel0  = (const float*)d_in[2];
    const float* brel0  = (const float*)d_in[3];
    const float* Wroot0 = (const float*)d_in[4];
    const float* Wrel1  = (const float*)d_in[5];
    const float* brel1  = (const float*)d_in[6];
    const float* Wroot1 = (const float*)d_in[7];
    const float* Wrel2  = (const float*)d_in[8];
    const float* brel2  = (const float*)d_in[9];
    const float* Wroot2 = (const float*)d_in[10];
    const float* Wc0    = (const float*)d_in[11];
    const float* bc0    = (const float*)d_in[12];
    const float* Wc1    = (const float*)d_in[13];
    const float* bc1    = (const float*)d_in[14];

    const int* src = ei;
    const int* dst = ei + N_EDGES;

    char* w = (char*)d_ws;
    auto alloc = [&](size_t bytes) {
        char* p = w;
        w += (bytes + 255) & ~(size_t)255;
        return (void*)p;
    };
    int* cursor  = (int*)alloc((size_t)N_NODES * 4);
    int* offsets = (int*)alloc(((size_t)N_NODES + 1) * 4);
    int* blksum  = (int*)alloc(1024 * 4);
    int* csr     = (int*)alloc((size_t)N_EDGES * 4);
    unsigned short* x_bf   = (unsigned short*)alloc((size_t)N_NODES * HID * 2);
    unsigned short* agg_bf = (unsigned short*)alloc((size_t)N_NODES * HID * 2);
    unsigned short* hA     = (unsigned short*)alloc((size_t)N_NODES * HID * 2);
    unsigned short* hB     = (unsigned short*)alloc((size_t)N_NODES * HID * 2);
    unsigned short* wtRel0  = (unsigned short*)alloc(128 * 128 * 2);
    unsigned short* wtRoot0 = (unsigned short*)alloc(128 * 128 * 2);
    unsigned short* wtRel1  = (unsigned short*)alloc(128 * 128 * 2);
    unsigned short* wtRoot1 = (unsigned short*)alloc(128 * 128 * 2);
    unsigned short* wtRel2  = (unsigned short*)alloc(128 * 128 * 2);
    unsigned short* wtRoot2 = (unsigned short*)alloc(128 * 128 * 2);
    unsigned short* wtC0    = (unsigned short*)alloc(128 * 128 * 2);
    unsigned short* wtC1    = (unsigned short*)alloc(32 * 128 * 2);

    hipMemsetAsync(cursor, 0, (size_t)N_NODES * 4, stream);
    const int eb = (N_EDGES + 255) / 256;
    const int sb = (N_NODES + 1023) / 1024;
    k_hist<<<eb, 256, 0, stream>>>(dst, cursor, N_EDGES);
    k_scan1<<<sb, 1024, 0, stream>>>(cursor, offsets, blksum, N_NODES);
    k_scan2<<<1, 1024, 0, stream>>>(blksum, sb);
    k_scan3<<<sb, 1024, 0, stream>>>(offsets, blksum, cursor, N_NODES, N_EDGES);
    k_fill<<<eb, 256, 0, stream>>>(src, dst, cursor, csr, N_EDGES);

    // casts + weight prep
    k_cast<<<(N_NODES * HID / 8 + 255) / 256, 256, 0, stream>>>(x, x_bf, N_NODES * HID / 8);
    {
        WPrepArgs a;
        a.src[0] = Wrel0;  a.dst[0] = wtRel0;  a.Ndim[0] = 128;
        a.src[1] = Wroot0; a.dst[1] = wtRoot0; a.Ndim[1] = 128;
        a.src[2] = Wrel1;  a.dst[2] = wtRel1;  a.Ndim[2] = 128;
        a.src[3] = Wroot1; a.dst[3] = wtRoot1; a.Ndim[3] = 128;
        a.src[4] = Wrel2;  a.dst[4] = wtRel2;  a.Ndim[4] = 128;
        a.src[5] = Wroot2; a.dst[5] = wtRoot2; a.Ndim[5] = 128;
        a.src[6] = Wc0;    a.dst[6] = wtC0;    a.Ndim[6] = 128;
        k_prep_w<<<7, 256, 0, stream>>>(a);
        WPrepArgs b;
        b.src[0] = Wc1; b.dst[0] = wtC1; b.Ndim[0] = 32;
        for (int i = 1; i < 7; ++i) { b.src[i] = Wc1; b.dst[i] = wtC1; b.Ndim[i] = 32; }
        k_prep_w<<<1, 256, 0, stream>>>(b);
    }

    const int ab = (N_NODES + 3) / 4;
    const int gb = (N_NODES + 127) / 128;

    // layer 0
    k_agg_bf<<<ab, 256, 0, stream>>>(x_bf, offsets, csr, agg_bf, N_NODES);
    k_mfma128<<<gb, 256, 0, stream>>>(agg_bf, wtRel0, x_bf, wtRoot0, brel0, hA, N_NODES, 1);
    // layer 1
    k_agg_bf<<<ab, 256, 0, stream>>>(hA, offsets, csr, agg_bf, N_NODES);
    k_mfma128<<<gb, 256, 0, stream>>>(agg_bf, wtRel1, hA, wtRoot1, brel1, hB, N_NODES, 1);
    // layer 2
    k_agg_bf<<<ab, 256, 0, stream>>>(hB, offsets, csr, agg_bf, N_NODES);
    k_mfma128<<<gb, 256, 0, stream>>>(agg_bf, wtRel2, hB, wtRoot2, brel2, hA, N_NODES, 1);
    // classifier hidden
    k_mfma128<<<gb, 256, 0, stream>>>(hA, wtC0, nullptr, nullptr, bc0, hB, N_NODES, 1);
    // classifier out
    k_mfma32<<<gb, 256, 0, stream>>>(hB, wtC1, bc1, (float*)d_out, N_NODES);
}

// Round 4
// 448.352 us; speedup vs baseline: 2.3195x; 1.2625x over previous
//
#include <hip/hip_runtime.h>
#include <cstdint>

#define N_NODES 100000
#define N_EDGES 1600000
#define HID 128
#define NT 32

// bucketed CSR build params
#define BSHIFT 7                      // 128 nodes per bucket
#define NB 782                        // ceil(100000 / 128)
#define NBLK_B 128                    // blocks in hist/scatter passes
#define EPB 12544                     // edges per block (= 256 * 49)
#define ITER_B 49

typedef __attribute__((ext_vector_type(8))) short short8v;
typedef __attribute__((ext_vector_type(4))) float f32x4;

__device__ inline unsigned short f2bf(float f) {
    union { float f; unsigned u; } v; v.f = f;
    unsigned r = v.u + 0x7FFF + ((v.u >> 16) & 1);
    return (unsigned short)(r >> 16);
}
__device__ inline float bf2f(unsigned short u) {
    union { unsigned u; float f; } v; v.u = ((unsigned)u) << 16; return v.f;
}

// ---------------- bucketed CSR build ----------------
// Pass A: bucket histogram
__global__ __launch_bounds__(256) void k_bhist(const int* __restrict__ dst,
                                               int* __restrict__ bcount, int n) {
    __shared__ int lh[NB];
    const int t = threadIdx.x;
    for (int i = t; i < NB; i += 256) lh[i] = 0;
    __syncthreads();
    const int base = blockIdx.x * EPB;
    #pragma unroll 1
    for (int i = 0; i < ITER_B; ++i) {
        int e = base + i * 256 + t;
        if (e < n) atomicAdd(&lh[dst[e] >> BSHIFT], 1);
    }
    __syncthreads();
    for (int i = t; i < NB; i += 256)
        if (lh[i]) atomicAdd(&bcount[i], lh[i]);
}

// exclusive scan of NB bucket counts -> bases (and gcur copy)
__global__ void k_bscan(const int* __restrict__ bcount, int* __restrict__ bases,
                        int* __restrict__ gcur) {
    __shared__ int s[1024];
    const int tid = threadIdx.x;
    int v = (tid < NB) ? bcount[tid] : 0;
    s[tid] = v;
    __syncthreads();
    #pragma unroll 1
    for (int d = 1; d < 1024; d <<= 1) {
        int t = (tid >= d) ? s[tid - d] : 0;
        __syncthreads();
        s[tid] += t;
        __syncthreads();
    }
    if (tid < NB) {
        int e0 = s[tid] - v;
        bases[tid] = e0;
        gcur[tid] = e0;
    }
    if (tid == NB) bases[NB] = s[NB - 1];
}

// Pass B: scatter edges into bucket-grouped staging, packed (local<<17)|src
__global__ __launch_bounds__(256) void k_bscatter(const int* __restrict__ src,
                                                  const int* __restrict__ dst,
                                                  int* __restrict__ gcur,
                                                  unsigned* __restrict__ staged, int n) {
    __shared__ int lh[NB];
    __shared__ int lbase[NB];
    const int t = threadIdx.x;
    for (int i = t; i < NB; i += 256) lh[i] = 0;
    __syncthreads();
    const int base = blockIdx.x * EPB;
    #pragma unroll 1
    for (int i = 0; i < ITER_B; ++i) {
        int e = base + i * 256 + t;
        if (e < n) atomicAdd(&lh[dst[e] >> BSHIFT], 1);
    }
    __syncthreads();
    for (int i = t; i < NB; i += 256) {
        int c = lh[i];
        lbase[i] = c ? atomicAdd(&gcur[i], c) : 0;
        lh[i] = 0;   // reuse as running cursor
    }
    __syncthreads();
    #pragma unroll 1
    for (int i = 0; i < ITER_B; ++i) {
        int e = base + i * 256 + t;
        if (e < n) {
            int d = dst[e];
            int b = d >> BSHIFT;
            int p = lbase[b] + atomicAdd(&lh[b], 1);
            staged[p] = (unsigned)src[e] | ((unsigned)(d & 127) << 17);
        }
    }
}

// Pass C: per-bucket group-by-node; write csr segment + exact offsets
__global__ __launch_bounds__(256) void k_bgroup(const unsigned* __restrict__ staged,
                                                const int* __restrict__ bases,
                                                int* __restrict__ offsets,
                                                int* __restrict__ csr) {
    __shared__ int lh[128];
    __shared__ int lex[128];
    const int t = threadIdx.x;
    const int b = blockIdx.x;
    const int s0 = bases[b], s1 = bases[b + 1];
    const int cnt = s1 - s0;
    if (t < 128) lh[t] = 0;
    __syncthreads();
    for (int i = t; i < cnt; i += 256)
        atomicAdd(&lh[staged[s0 + i] >> 17], 1);
    __syncthreads();
    int myc = (t < 128) ? lh[t] : 0;
    if (t < 128) lex[t] = myc;
    __syncthreads();
    #pragma unroll 1
    for (int d = 1; d < 128; d <<= 1) {
        int add = 0;
        if (t < 128 && t >= d) add = lex[t - d];
        __syncthreads();
        if (t < 128) lex[t] += add;
        __syncthreads();
    }
    if (t < 128) {
        int excl = lex[t] - myc;   // exclusive prefix within bucket
        lex[t] = excl;
        int node = (b << BSHIFT) + t;
        if (node < N_NODES) offsets[node] = s0 + excl;
        lh[t] = 0;                 // reuse as per-node cursor
    }
    if (b == 0 && t == 0) offsets[N_NODES] = N_EDGES;
    __syncthreads();
    for (int i = t; i < cnt; i += 256) {
        unsigned v = staged[s0 + i];
        int local = v >> 17;
        int p = s0 + lex[local] + atomicAdd(&lh[local], 1);
        csr[p] = (int)(v & 0x1FFFF);
    }
}

// ---------------- cast x -> bf16 ----------------
__global__ void k_cast(const float* __restrict__ in, unsigned short* __restrict__ out, int n8) {
    int i = blockIdx.x * 256 + threadIdx.x;
    if (i >= n8) return;
    const float4* p = reinterpret_cast<const float4*>(in + (size_t)i * 8);
    float4 a = p[0], b = p[1];
    union { unsigned short u[8]; uint4 v; } o;
    o.u[0] = f2bf(a.x); o.u[1] = f2bf(a.y); o.u[2] = f2bf(a.z); o.u[3] = f2bf(a.w);
    o.u[4] = f2bf(b.x); o.u[5] = f2bf(b.y); o.u[6] = f2bf(b.z); o.u[7] = f2bf(b.w);
    *reinterpret_cast<uint4*>(out + (size_t)i * 8) = o.v;
}

// ---------------- weight prep: Wt[n][k] = bf16(W[k][n]), K=128 ----------------
struct WPrepArgs {
    const float* src[7];
    unsigned short* dst[7];
    int Ndim[7];
};

__global__ void k_prep_w(WPrepArgs a) {
    int m = blockIdx.x;
    const float* s = a.src[m];
    unsigned short* d = a.dst[m];
    int N = a.Ndim[m];
    int total = 128 * N;
    for (int idx = threadIdx.x; idx < total; idx += 256) {
        int n = idx >> 7;       // 0..N-1
        int k = idx & 127;      // 0..127
        d[n * 128 + k] = f2bf(s[(size_t)k * N + n]);
    }
}

// ---------------- aggregation (pull over CSR, bf16) ----------------
__global__ void k_agg_bf(const unsigned short* __restrict__ X, const int* __restrict__ offsets,
                         const int* __restrict__ csr, unsigned short* __restrict__ agg, int n) {
    int node = blockIdx.x * 4 + (threadIdx.x >> 6);
    if (node >= n) return;
    int lane = threadIdx.x & 63;
    int e0 = offsets[node], e1 = offsets[node + 1];
    float ax = 0.f, ay = 0.f;
    int e = e0;
    for (; e + 4 <= e1; e += 4) {
        int s0 = csr[e], s1 = csr[e + 1], s2 = csr[e + 2], s3 = csr[e + 3];
        unsigned v0 = *reinterpret_cast<const unsigned*>(X + (size_t)s0 * HID + lane * 2);
        unsigned v1 = *reinterpret_cast<const unsigned*>(X + (size_t)s1 * HID + lane * 2);
        unsigned v2 = *reinterpret_cast<const unsigned*>(X + (size_t)s2 * HID + lane * 2);
        unsigned v3 = *reinterpret_cast<const unsigned*>(X + (size_t)s3 * HID + lane * 2);
        ax += bf2f((unsigned short)(v0 & 0xFFFF)) + bf2f((unsigned short)(v1 & 0xFFFF))
            + bf2f((unsigned short)(v2 & 0xFFFF)) + bf2f((unsigned short)(v3 & 0xFFFF));
        ay += bf2f((unsigned short)(v0 >> 16)) + bf2f((unsigned short)(v1 >> 16))
            + bf2f((unsigned short)(v2 >> 16)) + bf2f((unsigned short)(v3 >> 16));
    }
    for (; e < e1; ++e) {
        int s = csr[e];
        unsigned v = *reinterpret_cast<const unsigned*>(X + (size_t)s * HID + lane * 2);
        ax += bf2f((unsigned short)(v & 0xFFFF));
        ay += bf2f((unsigned short)(v >> 16));
    }
    unsigned pack = ((unsigned)f2bf(ay) << 16) | (unsigned)f2bf(ax);
    *reinterpret_cast<unsigned*>(agg + (size_t)node * HID + lane * 2) = pack;
}

// ---------------- MFMA dual-source GEMM ----------------
__global__ __launch_bounds__(256) void k_mfma128(
    const unsigned short* __restrict__ Xa, const unsigned short* __restrict__ WtA,
    const unsigned short* __restrict__ Xb, const unsigned short* __restrict__ WtB,
    const float* __restrict__ bias, unsigned short* __restrict__ Out,
    int M, int doRelu)
{
    __shared__ unsigned short wlds[128 * 136];

    const int t = threadIdx.x;
    const int lane = t & 63;
    const int w = t >> 6;
    const int r0 = blockIdx.x * 128;
    const int lrow = lane & 15;
    const int kg = lane >> 4;      // 0..3

    f32x4 acc[2][8];
    #pragma unroll
    for (int i = 0; i < 2; ++i)
        #pragma unroll
        for (int f = 0; f < 8; ++f) acc[i][f] = (f32x4){0.f, 0.f, 0.f, 0.f};

    #pragma unroll 1
    for (int sidx = 0; sidx < 2; ++sidx) {
        const unsigned short* X  = sidx ? Xb : Xa;
        const unsigned short* Wt = sidx ? WtB : WtA;
        if (!X) break;
        __syncthreads();
        {
            int n = t >> 1;
            int half = (t & 1) * 64;
            const unsigned short* srcp = Wt + (size_t)n * 128 + half;
            unsigned short* dstp = &wlds[n * 136 + half];
            #pragma unroll
            for (int j = 0; j < 8; ++j)
                *reinterpret_cast<uint4*>(dstp + j * 8) =
                    *reinterpret_cast<const uint4*>(srcp + j * 8);
        }
        __syncthreads();
        #pragma unroll 1
        for (int kc = 0; kc < 4; ++kc) {
            const int kb = kc * 32 + kg * 8;
            short8v a0 = {0,0,0,0,0,0,0,0}, a1 = {0,0,0,0,0,0,0,0};
            int row0 = r0 + w * 32 + lrow;
            int row1 = row0 + 16;
            if (row0 < M) a0 = *reinterpret_cast<const short8v*>(X + (size_t)row0 * 128 + kb);
            if (row1 < M) a1 = *reinterpret_cast<const short8v*>(X + (size_t)row1 * 128 + kb);
            #pragma unroll
            for (int f = 0; f < 8; ++f) {
                short8v b = *reinterpret_cast<const short8v*>(&wlds[(f * 16 + lrow) * 136 + kb]);
                acc[0][f] = __builtin_amdgcn_mfma_f32_16x16x32_bf16(a0, b, acc[0][f], 0, 0, 0);
                acc[1][f] = __builtin_amdgcn_mfma_f32_16x16x32_bf16(a1, b, acc[1][f], 0, 0, 0);
            }
        }
    }
    #pragma unroll
    for (int rr = 0; rr < 2; ++rr) {
        #pragma unroll
        for (int f = 0; f < 8; ++f) {
            int col = f * 16 + lrow;
            float bv = bias[col];
            #pragma unroll
            for (int reg = 0; reg < 4; ++reg) {
                int row = r0 + w * 32 + rr * 16 + kg * 4 + reg;
                if (row < M) {
                    float v = acc[rr][f][reg] + bv;
                    if (doRelu) v = fmaxf(v, 0.f);
                    Out[(size_t)row * 128 + col] = f2bf(v);
                }
            }
        }
    }
}

// ---------------- MFMA head: Out[M x 32] f32 = X@Wc1 + bc1 ----------------
__global__ __launch_bounds__(256) void k_mfma32(
    const unsigned short* __restrict__ X, const unsigned short* __restrict__ Wt,
    const float* __restrict__ bias, float* __restrict__ Out, int M)
{
    __shared__ unsigned short wlds[32 * 136];

    const int t = threadIdx.x;
    const int lane = t & 63;
    const int w = t >> 6;
    const int r0 = blockIdx.x * 128;
    const int lrow = lane & 15;
    const int kg = lane >> 4;

    {
        int n = t >> 3;               // 0..31
        int seg = (t & 7) * 16;       // 0..112 step 16
        *reinterpret_cast<uint4*>(&wlds[n * 136 + seg]) =
            *reinterpret_cast<const uint4*>(Wt + (size_t)n * 128 + seg);
        *reinterpret_cast<uint4*>(&wlds[n * 136 + seg + 8]) =
            *reinterpret_cast<const uint4*>(Wt + (size_t)n * 128 + seg + 8);
    }
    __syncthreads();

    f32x4 acc[2][2];
    #pragma unroll
    for (int i = 0; i < 2; ++i)
        #pragma unroll
        for (int f = 0; f < 2; ++f) acc[i][f] = (f32x4){0.f, 0.f, 0.f, 0.f};

    #pragma unroll 1
    for (int kc = 0; kc < 4; ++kc) {
        const int kb = kc * 32 + kg * 8;
        short8v a0 = {0,0,0,0,0,0,0,0}, a1 = {0,0,0,0,0,0,0,0};
        int row0 = r0 + w * 32 + lrow;
        int row1 = row0 + 16;
        if (row0 < M) a0 = *reinterpret_cast<const short8v*>(X + (size_t)row0 * 128 + kb);
        if (row1 < M) a1 = *reinterpret_cast<const short8v*>(X + (size_t)row1 * 128 + kb);
        #pragma unroll
        for (int f = 0; f < 2; ++f) {
            short8v b = *reinterpret_cast<const short8v*>(&wlds[(f * 16 + lrow) * 136 + kb]);
            acc[0][f] = __builtin_amdgcn_mfma_f32_16x16x32_bf16(a0, b, acc[0][f], 0, 0, 0);
            acc[1][f] = __builtin_amdgcn_mfma_f32_16x16x32_bf16(a1, b, acc[1][f], 0, 0, 0);
        }
    }
    #pragma unroll
    for (int rr = 0; rr < 2; ++rr) {
        #pragma unroll
        for (int f = 0; f < 2; ++f) {
            int col = f * 16 + lrow;
            float bv = bias[col];
            #pragma unroll
            for (int reg = 0; reg < 4; ++reg) {
                int row = r0 + w * 32 + rr * 16 + kg * 4 + reg;
                if (row < M) Out[(size_t)row * 32 + col] = acc[rr][f][reg] + bv;
            }
        }
    }
}

extern "C" void kernel_launch(void* const* d_in, const int* in_sizes, int n_in,
                              void* d_out, int out_size, void* d_ws, size_t ws_size,
                              hipStream_t stream) {
    (void)in_sizes; (void)n_in; (void)out_size; (void)ws_size;

    const float* x      = (const float*)d_in[0];
    const int*   ei     = (const int*)d_in[1];
    const float* Wrel0  = (const float*)d_in[2];
    const float* brel0  = (const float*)d_in[3];
    const float* Wroot0 = (const float*)d_in[4];
    const float* Wrel1  = (const float*)d_in[5];
    const float* brel1  = (const float*)d_in[6];
    const float* Wroot1 = (const float*)d_in[7];
    const float* Wrel2  = (const float*)d_in[8];
    const float* brel2  = (const float*)d_in[9];
    const float* Wroot2 = (const float*)d_in[10];
    const float* Wc0    = (const float*)d_in[11];
    const float* bc0    = (const float*)d_in[12];
    const float* Wc1    = (const float*)d_in[13];
    const float* bc1    = (const float*)d_in[14];

    const int* src = ei;
    const int* dst = ei + N_EDGES;

    char* w = (char*)d_ws;
    auto alloc = [&](size_t bytes) {
        char* p = w;
        w += (bytes + 255) & ~(size_t)255;
        return (void*)p;
    };
    int* bcount  = (int*)alloc((size_t)NB * 4);
    int* bases   = (int*)alloc(((size_t)NB + 1) * 4);
    int* gcur    = (int*)alloc((size_t)NB * 4);
    int* offsets = (int*)alloc(((size_t)N_NODES + 1) * 4);
    unsigned* staged = (unsigned*)alloc((size_t)N_EDGES * 4);
    int* csr     = (int*)alloc((size_t)N_EDGES * 4);
    unsigned short* x_bf   = (unsigned short*)alloc((size_t)N_NODES * HID * 2);
    unsigned short* agg_bf = (unsigned short*)alloc((size_t)N_NODES * HID * 2);
    unsigned short* hA     = (unsigned short*)alloc((size_t)N_NODES * HID * 2);
    unsigned short* hB     = (unsigned short*)alloc((size_t)N_NODES * HID * 2);
    unsigned short* wtRel0  = (unsigned short*)alloc(128 * 128 * 2);
    unsigned short* wtRoot0 = (unsigned short*)alloc(128 * 128 * 2);
    unsigned short* wtRel1  = (unsigned short*)alloc(128 * 128 * 2);
    unsigned short* wtRoot1 = (unsigned short*)alloc(128 * 128 * 2);
    unsigned short* wtRel2  = (unsigned short*)alloc(128 * 128 * 2);
    unsigned short* wtRoot2 = (unsigned short*)alloc(128 * 128 * 2);
    unsigned short* wtC0    = (unsigned short*)alloc(128 * 128 * 2);
    unsigned short* wtC1    = (unsigned short*)alloc(32 * 128 * 2);

    // ---- CSR build (bucketed counting sort) ----
    hipMemsetAsync(bcount, 0, (size_t)NB * 4, stream);
    k_bhist<<<NBLK_B, 256, 0, stream>>>(dst, bcount, N_EDGES);
    k_bscan<<<1, 1024, 0, stream>>>(bcount, bases, gcur);
    k_bscatter<<<NBLK_B, 256, 0, stream>>>(src, dst, gcur, staged, N_EDGES);
    k_bgroup<<<NB, 256, 0, stream>>>(staged, bases, offsets, csr);

    // ---- casts + weight prep ----
    k_cast<<<(N_NODES * HID / 8 + 255) / 256, 256, 0, stream>>>(x, x_bf, N_NODES * HID / 8);
    {
        WPrepArgs a;
        a.src[0] = Wrel0;  a.dst[0] = wtRel0;  a.Ndim[0] = 128;
        a.src[1] = Wroot0; a.dst[1] = wtRoot0; a.Ndim[1] = 128;
        a.src[2] = Wrel1;  a.dst[2] = wtRel1;  a.Ndim[2] = 128;
        a.src[3] = Wroot1; a.dst[3] = wtRoot1; a.Ndim[3] = 128;
        a.src[4] = Wrel2;  a.dst[4] = wtRel2;  a.Ndim[4] = 128;
        a.src[5] = Wroot2; a.dst[5] = wtRoot2; a.Ndim[5] = 128;
        a.src[6] = Wc0;    a.dst[6] = wtC0;    a.Ndim[6] = 128;
        k_prep_w<<<7, 256, 0, stream>>>(a);
        WPrepArgs b;
        b.src[0] = Wc1; b.dst[0] = wtC1; b.Ndim[0] = 32;
        for (int i = 1; i < 7; ++i) { b.src[i] = Wc1; b.dst[i] = wtC1; b.Ndim[i] = 32; }
        k_prep_w<<<1, 256, 0, stream>>>(b);
    }

    const int ab = (N_NODES + 3) / 4;
    const int gb = (N_NODES + 127) / 128;

    // layer 0
    k_agg_bf<<<ab, 256, 0, stream>>>(x_bf, offsets, csr, agg_bf, N_NODES);
    k_mfma128<<<gb, 256, 0, stream>>>(agg_bf, wtRel0, x_bf, wtRoot0, brel0, hA, N_NODES, 1);
    // layer 1
    k_agg_bf<<<ab, 256, 0, stream>>>(hA, offsets, csr, agg_bf, N_NODES);
    k_mfma128<<<gb, 256, 0, stream>>>(agg_bf, wtRel1, hA, wtRoot1, brel1, hB, N_NODES, 1);
    // layer 2
    k_agg_bf<<<ab, 256, 0, stream>>>(hB, offsets, csr, agg_bf, N_NODES);
    k_mfma128<<<gb, 256, 0, stream>>>(agg_bf, wtRel2, hB, wtRoot2, brel2, hA, N_NODES, 1);
    // classifier hidden
    k_mfma128<<<gb, 256, 0, stream>>>(hA, wtC0, nullptr, nullptr, bc0, hB, N_NODES, 1);
    // classifier out
    k_mfma32<<<gb, 256, 0, stream>>>(hB, wtC1, bc1, (float*)d_out, N_NODES);
}